// Round 17
// baseline (67.589 us; speedup 1.0000x reference)
//
#include <hip/hip_runtime.h>
#include <math.h>

#define T_N   1000
#define L_N   1024
#define N_B   64
#define PADU  288          // zero-pad u32s (f16-pairs) below live P region
#define LOG2E 1.4426950408889634f
#define LN2   0.6931471805599453f
#define DT_F  0.01f
#define KCUT  5.0f         // tap cutoff: q negligible where 2^t*s > KCUT (e^-5)
#define STEP_OVH 24        // per-step fixed overhead in conv-iter units (cost model)

typedef unsigned int u32;
typedef _Float16 h2_t __attribute__((ext_vector_type(2)));

__device__ __forceinline__ float dot2f(u32 t, u32 w, float c) {
#if __has_builtin(__builtin_amdgcn_fdot2)
    return __builtin_amdgcn_fdot2(__builtin_bit_cast(h2_t, t),
                                  __builtin_bit_cast(h2_t, w), c, false);
#else
    h2_t a = __builtin_bit_cast(h2_t, t), b = __builtin_bit_cast(h2_t, w);
    return fmaf((float)a.x, (float)b.x, fmaf((float)a.y, (float)b.y, c));
#endif
}

__device__ __forceinline__ u32 pk(float lo, float hi) {
    h2_t v; v.x = (_Float16)lo; v.y = (_Float16)hi;
    return __builtin_bit_cast(u32, v);
}

// ---------------- Kernel A: sinr + per-link cost estimate ----------------
__global__ __launch_bounds__(256) void sinr_kernel(const float* __restrict__ powers,
                                                   const float* __restrict__ pathloss,
                                                   float* __restrict__ sinr,
                                                   float* __restrict__ out,
                                                   int* __restrict__ cost) {
    __shared__ float svb[2][N_B];
    const int tid  = threadIdx.x;
    const int wv   = tid >> 6;
    const int lane = tid & 63;
    const int i    = 2 * blockIdx.x + (wv & 1);
    const int n0   = 32 * (wv >> 1);

    if (blockIdx.x == 0 && tid == 0) out[0] = 0.f;   // scan runs after: safe

    const float4* row4g = (const float4*)(pathloss + i * L_N);
    float4 row[4];
    #pragma unroll
    for (int k = 0; k < 4; ++k) row[k] = row4g[lane + 64 * k];
    const float pii = pathloss[i * L_N + i];

    for (int nn = 0; nn < 32; nn += 4) {
        float part[4];
        #pragma unroll
        for (int u = 0; u < 4; ++u) {
            const float4* pr4 = (const float4*)(powers + (n0 + nn + u) * L_N);
            float s = 0.f;
            #pragma unroll
            for (int k = 0; k < 4; ++k) {
                float4 p = pr4[lane + 64 * k];
                s = fmaf(row[k].x, p.x, s);
                s = fmaf(row[k].y, p.y, s);
                s = fmaf(row[k].z, p.z, s);
                s = fmaf(row[k].w, p.w, s);
            }
            part[u] = s;
        }
        #pragma unroll
        for (int off = 32; off > 0; off >>= 1) {
            part[0] += __shfl_down(part[0], off, 64);
            part[1] += __shfl_down(part[1], off, 64);
            part[2] += __shfl_down(part[2], off, 64);
            part[3] += __shfl_down(part[3], off, 64);
        }
        if (lane == 0) {
            #pragma unroll
            for (int u = 0; u < 4; ++u) {
                const int n = n0 + nn + u;
                float yii = pii * powers[n * L_N + i];
                float v   = yii / (part[u] - yii + 1.0f);
                sinr[n * L_N + i] = v;
                svb[wv & 1][n] = v;
            }
        }
    }
    __syncthreads();

    if (tid < 2) {
        const float* svp = svb[tid];
        int A = 0, cv = 0;
        for (int n = 1; n < N_B; ++n) {
            const float s = svp[n];
            const int kstar = (int)(100.f * log2f(KCUT / s)) + 1;
            int dmin = 999 - kstar; if (dmin < 0) dmin = 0;
            const int Aprev = A;
            A += dmin;
            if (A > 999) break;
            const int k0 = dmin >> 3;
            int kend = ((1023 - Aprev) >> 3) + 1; if (kend > 126) kend = 126;
            int trip = kend - k0; if (trip < 0) trip = 0;
            cv += trip + STEP_OVH;
        }
        cost[2 * blockIdx.x + tid] = cv;
    }
}

// ---------------- Kernel A2: rank links by cost -> linkOfRank permutation ----------------
__global__ __launch_bounds__(64) void rank_kernel(const int* __restrict__ cost,
                                                  int* __restrict__ linkOfRank) {
    __shared__ int cl[L_N];
    const int l = 64 * blockIdx.x + threadIdx.x;
    for (int j = threadIdx.x; j < L_N; j += 64) cl[j] = cost[j];
    __syncthreads();
    const int c = cl[l];
    int cnt = 0;
    #pragma unroll 8
    for (int j = 0; j < L_N; ++j) {
        const int cj = cl[j];
        cnt += (cj > c) || (cj == c && j < l);
    }
    linkOfRank[cnt] = l;
}

// 8 dot2: outputs j0..j0+7 against one tap pair (TE) and its shifted twin (TO)
#define D8(W0, W1, W2, W3, TE, TO) do {                                      \
    a0 = dot2f(TE, W0, a0); a1 = dot2f(TO, W0, a1);                          \
    a2 = dot2f(TE, W1, a2); a3 = dot2f(TO, W1, a3);                          \
    a4 = dot2f(TE, W2, a4); a5 = dot2f(TO, W2, a5);                          \
    a6 = dot2f(TE, W3, a6); a7 = dot2f(TO, W3, a7);                          \
} while (0)

// ---------------- Kernel B: cost-spread f16 dot2 scan ----------------
// Block b -> rank (255*b) mod 1024 -> link. 255 is odd => bijection; ranks in
// ANY power-of-2 co-residency group are spread by 255*2^k mod 1024 (>=255 for
// k<=7), so heavy links never cluster regardless of the dispatch mapping.
__global__ __launch_bounds__(128) void scan_kernel(const float* __restrict__ powers,
                                                   const float* __restrict__ sinr,
                                                   float* __restrict__ out,
                                                   const int* __restrict__ linkOfRank) {
    __shared__ __align__(16) float p2t[1024];
    __shared__ __align__(16) u32 P[2][PADU + 512];
    __shared__ __align__(16) u32 T[512];
    __shared__ float sv[N_B];
    __shared__ float tails[N_B];
    __shared__ u32 bridge;   // f16 bits of Q[511] (light wave lane 63's out)

    const int b    = blockIdx.x;
    const int rank = (255 * b) & 1023;
    const int l    = linkOfRank[rank];

    const int tid  = threadIdx.x;                 // 0..127
    const int lane = tid & 63;
    const int wr   = ((tid >> 6) ^ (b & 1) ^ ((b >> 3) & 1)) & 1;

    // 2^t table (f32): 128 threads x 2 quads
    #pragma unroll
    for (int m = 0; m < 2; ++m) {
        const int jq = tid + 128 * m;
        float4 v;
        v.x = exp2f(0.01f * (float)(4 * jq + 0));
        v.y = exp2f(0.01f * (float)(4 * jq + 1));
        v.z = exp2f(0.01f * (float)(4 * jq + 2));
        v.w = exp2f(0.01f * (float)(4 * jq + 3));
        *(float4*)&p2t[4 * jq] = v;
    }
    if (tid < N_B) { sv[tid] = sinr[tid * L_N + l]; tails[tid] = 0.f; }
    for (int i = tid; i < PADU; i += 128) { P[0][i] = 0; P[1][i] = 0; }
    if (tid >= 125) *(uint4*)&T[4 * tid] = make_uint4(0u, 0u, 0u, 0u);  // d>=1000: permanent zeros
    __syncthreads();

    // ---- init: Q1 -> P[0] (f16 pairs) ----
    {
        const float s0l = sv[0] * LOG2E;
        const int jb = 8 * tid;
        float q[9];
        #pragma unroll
        for (int ii = 0; ii < 9; ++ii) {
            const int j = jb - 1 + ii;
            float v = 0.f;
            if (j >= 0 && j < T_N) v = 1.f - exp2f((1.f - p2t[j]) * s0l);
            q[ii] = v;
        }
        uint4 w;
        w.x = pk(q[1], q[0]); w.y = pk(q[3], q[2]);
        w.z = pk(q[5], q[4]); w.w = pk(q[7], q[6]);
        *(uint4*)&P[0][PADU + 4 * tid] = w;
        if (tid == 124) tails[0] = q[8];          // Q1[999]
    }
    __syncthreads();

    const int NB   = wr ? 126 : 64;               // 4-tap blocks (p-range)
    const int j0   = 512 * wr + 8 * lane;         // first output of this lane
    const int s4   = j0 >> 3;                     // window quad index
    const int jmxW = 512 * wr + 511;              // last output of this wave

    int A  = 0;                                   // support lower bound of Q_prev
    int cb = 0;
    for (int n = 1; n < N_B; ++n) {
        // ---- support bookkeeping (uniform across block) ----
        const float s = sv[n];
        const int kstar = (int)(100.f * log2f(KCUT / s)) + 1;   // conservative
        int dmin = 999 - kstar; if (dmin < 0) dmin = 0;
        const int Aprev = A;
        A += dmin;
        if (A > 999) break;                        // link dead: remaining tails = 0
        const int k0 = dmin >> 3;
        int kend = ((jmxW - Aprev) >> 3) + 1;      // per-wave upper tap bound
        if (kend > NB) kend = NB;
        int kcap = ((1023 - Aprev) >> 3) + 2;      // heavy kend + 1 (prefetch reach)
        if (kcap > 124) kcap = 124;

        // ---- phase R: taps (only quads [k0, kcap]) + bridge fix ----
        if (n >= 2 && wr == 1 && lane == 0)
            ((unsigned short*)&P[cb][PADU + 256])[1] = (unsigned short)bridge;
        if (tid >= k0 && tid <= kcap) {
            const float sl   = s * LOG2E;
            const float smul = s * LN2 * DT_F;
            const int t8 = 8 * tid;                // < 1000 since tid <= 124
            float4 pa = *(const float4*)&p2t[996 - t8];
            float4 pb = *(const float4*)&p2t[992 - t8];
            float r0 = smul * pa.w * exp2f((1.f - pa.w) * sl);
            float r1 = smul * pa.z * exp2f((1.f - pa.z) * sl);
            float r2 = smul * pa.y * exp2f((1.f - pa.y) * sl);
            float r3 = smul * pa.x * exp2f((1.f - pa.x) * sl);
            float r4 = smul * pb.w * exp2f((1.f - pb.w) * sl);
            float r5 = smul * pb.z * exp2f((1.f - pb.z) * sl);
            float r6 = smul * pb.y * exp2f((1.f - pb.y) * sl);
            float r7 = smul * pb.x * exp2f((1.f - pb.x) * sl);
            uint4 tw;
            tw.x = pk(r0, r1); tw.y = pk(r2, r3);
            tw.z = pk(r4, r5); tw.w = pk(r6, r7);
            *(uint4*)&T[4 * tid] = tw;
        }
        __syncthreads();

        // ---- phase C: conv over tap blocks k0..kend-1 ----
        const u32*   Pc = &P[cb][PADU];
        const uint4* P4 = (const uint4*)Pc;
        const uint4* T4 = (const uint4*)T;

        float a0 = 0.f, a1 = 0.f, a2 = 0.f, a3 = 0.f;
        float a4 = 0.f, a5 = 0.f, a6 = 0.f, a7 = 0.f;

        if (k0 < kend) {
            uint4 wc = P4[s4 - k0], wn = P4[s4 - k0 - 1];
            uint4 tc = T4[k0],      tn = T4[k0 + 1];

            #pragma unroll 2
            for (int k = k0; k < kend; ++k) {
                uint4 wnn = P4[s4 - k - 2];       // prefetch (pad-safe)
                uint4 tnn = T4[k + 2];            // broadcast (<=127 in bounds)
                u32 al;
                al = (tc.x >> 16) | (tc.y << 16);
                D8(wc.x, wc.y, wc.z, wc.w, tc.x, al);
                al = (tc.y >> 16) | (tc.z << 16);
                D8(wn.w, wc.x, wc.y, wc.z, tc.y, al);
                al = (tc.z >> 16) | (tc.w << 16);
                D8(wn.z, wn.w, wc.x, wc.y, tc.z, al);
                al = (tc.w >> 16) | (tn.x << 16);
                D8(wn.y, wn.z, wn.w, wc.x, tc.w, al);
                wc = wn; wn = wnn; tc = tn; tn = tnn;
            }
        }

        // ---- epilogue: pack to f16 pairs, write P_next ----
        {
            float qm1 = __shfl_up(a7, 1, 64);     // Q[j0-1] from neighbor
            if (lane == 0) qm1 = 0.f;             // light: Q[-1]=0; heavy: via bridge
            float b0 = (j0 + 0 < T_N) ? a0 : 0.f;
            float b1 = (j0 + 1 < T_N) ? a1 : 0.f;
            float b2 = (j0 + 2 < T_N) ? a2 : 0.f;
            float b3 = (j0 + 3 < T_N) ? a3 : 0.f;
            float b4 = (j0 + 4 < T_N) ? a4 : 0.f;
            float b5 = (j0 + 5 < T_N) ? a5 : 0.f;
            float b6 = (j0 + 6 < T_N) ? a6 : 0.f;
            float bm = (j0     <= T_N) ? qm1 : 0.f;
            uint4 w;
            w.x = pk(b0, bm); w.y = pk(b2, b1);
            w.z = pk(b4, b3); w.w = pk(b6, b5);
            *(uint4*)&P[cb ^ 1][PADU + 4 * s4] = w;
            if (wr == 1 && lane == 60) tails[n] = a7;   // out[999]
            if (wr == 0 && lane == 63)
                bridge = (u32)__builtin_bit_cast(unsigned short, (_Float16)a7); // Q[511]
        }
        __syncthreads();
        cb ^= 1;
    }
    __syncthreads();

    // ---- per-link loss contribution -> global atomic accumulate ----
    if (tid < N_B) {
        float tl   = tails[tid];
        float term = (tid < N_B - 1) ? tl * (powers[(tid + 1) * L_N + l] + 1.0f) : tl;
        if (tid == 0) term += powers[l] + 1.0f;
        #pragma unroll
        for (int off = 32; off > 0; off >>= 1) term += __shfl_down(term, off, 64);
        if (tid == 0) atomicAdd(out, term);
    }
}

extern "C" void kernel_launch(void* const* d_in, const int* in_sizes, int n_in,
                              void* d_out, int out_size, void* d_ws, size_t ws_size,
                              hipStream_t stream) {
    const float* powers   = (const float*)d_in[0];
    const float* pathloss = (const float*)d_in[1];
    float* sinr       = (float*)d_ws;                      // 64*1024 floats
    int*   cost       = (int*)(sinr + N_B * L_N);          // 1024 ints
    int*   linkOfRank = cost + L_N;                        // 1024 ints
    float* out        = (float*)d_out;

    sinr_kernel<<<dim3(L_N / 2), dim3(256), 0, stream>>>(powers, pathloss, sinr, out, cost);
    rank_kernel<<<dim3(16), dim3(64), 0, stream>>>(cost, linkOfRank);
    scan_kernel<<<dim3(L_N), dim3(128), 0, stream>>>(powers, sinr, out, linkOfRank);
}

// Round 18
// 40.963 us; speedup vs baseline: 1.6500x; 1.6500x over previous
//
#include <hip/hip_runtime.h>
#include <math.h>

#define T_N   1000
#define L_N   1024
#define N_B   64
#define PADU  288          // zero-pad u32s (f16-pairs) below live P region
#define LOG2E 1.4426950408889634f
#define LN2   0.6931471805599453f
#define DT_F  0.01f
#define KCUT  5.0f         // tap cutoff: q negligible where 2^t*s > KCUT (e^-5)

typedef unsigned int u32;
typedef _Float16 h2_t __attribute__((ext_vector_type(2)));

__device__ __forceinline__ float dot2f(u32 t, u32 w, float c) {
#if __has_builtin(__builtin_amdgcn_fdot2)
    return __builtin_amdgcn_fdot2(__builtin_bit_cast(h2_t, t),
                                  __builtin_bit_cast(h2_t, w), c, false);
#else
    h2_t a = __builtin_bit_cast(h2_t, t), b = __builtin_bit_cast(h2_t, w);
    return fmaf((float)a.x, (float)b.x, fmaf((float)a.y, (float)b.y, c));
#endif
}

__device__ __forceinline__ u32 pk(float lo, float hi) {
    h2_t v; v.x = (_Float16)lo; v.y = (_Float16)hi;
    return __builtin_bit_cast(u32, v);
}

// 8 dot2: outputs j0..j0+7 against one tap pair (TE) and its shifted twin (TO)
#define D8(W0, W1, W2, W3, TE, TO) do {                                      \
    a0 = dot2f(TE, W0, a0); a1 = dot2f(TO, W0, a1);                          \
    a2 = dot2f(TE, W1, a2); a3 = dot2f(TO, W1, a3);                          \
    a4 = dot2f(TE, W2, a4); a5 = dot2f(TO, W2, a5);                          \
    a6 = dot2f(TE, W3, a6); a7 = dot2f(TO, W3, a7);                          \
} while (0)

// ---------------- Fused kernel: per-link sinr + f16 dot2 support-tracked scan ----------------
// One block per link (128 thr, 2 waves). Phase 0 computes sv[n] = sinr[n,l]
// in-block (pathloss row in regs, powers streamed from L2). Then the R15 scan:
// P[m]=f16x2(lo=Q[2m],hi=Q[2m-1]); T[p]=f16x2(lo=r[2p],hi=r[2p+1]).
// Support: r_n[d]==0 for d<dmin=999-k*(s), k*=100*log2(KCUT/s); A+=dmin,
// dead (A>999)->break; two-sided trip bound per wave; kcap-trimmed r-gen.
__global__ __launch_bounds__(128) void scan_kernel(const float* __restrict__ powers,
                                                   const float* __restrict__ pathloss,
                                                   float* __restrict__ out) {
    __shared__ __align__(16) float p2t[1024];
    __shared__ __align__(16) float rowL[1024];
    __shared__ __align__(16) u32 P[2][PADU + 512];
    __shared__ __align__(16) u32 T[512];
    __shared__ float sv[N_B];
    __shared__ float tails[N_B];
    __shared__ u32 bridge;   // f16 bits of Q[511] (light wave lane 63's out)

    const int l    = blockIdx.x;
    const int tid  = threadIdx.x;                 // 0..127
    const int lane = tid & 63;
    const int wv   = tid >> 6;                    // physical wave 0/1
    const int wr   = (wv ^ (blockIdx.x & 1) ^ ((blockIdx.x >> 3) & 1)) & 1;

    // ---- phase 0a: stage pathloss row l; 2^t table ----
    {
        const float4* rg = (const float4*)(pathloss + l * L_N);
        *(float4*)&rowL[4 * tid]       = rg[tid];
        *(float4*)&rowL[4 * (tid+128)] = rg[tid + 128];
        #pragma unroll
        for (int m = 0; m < 2; ++m) {
            const int jq = tid + 128 * m;
            float4 v;
            v.x = exp2f(0.01f * (float)(4 * jq + 0));
            v.y = exp2f(0.01f * (float)(4 * jq + 1));
            v.z = exp2f(0.01f * (float)(4 * jq + 2));
            v.w = exp2f(0.01f * (float)(4 * jq + 3));
            *(float4*)&p2t[4 * jq] = v;
        }
    }
    for (int i = tid; i < PADU; i += 128) { P[0][i] = 0; P[1][i] = 0; }
    if (tid >= 125) *(uint4*)&T[4 * tid] = make_uint4(0u, 0u, 0u, 0u);  // d>=1000: permanent zeros
    __syncthreads();

    // ---- phase 0b: sv[n] = sinr[n,l]; wave wv covers n in [32wv, 32wv+32) ----
    {
        float4 row[4];
        #pragma unroll
        for (int k = 0; k < 4; ++k) row[k] = *(const float4*)&rowL[4 * (lane + 64 * k)];
        const float pii = rowL[l];
        const int n0 = 32 * wv;
        for (int nn = 0; nn < 32; nn += 2) {
            float part[2];
            #pragma unroll
            for (int u = 0; u < 2; ++u) {
                const float4* pr4 = (const float4*)(powers + (n0 + nn + u) * L_N);
                float s = 0.f;
                #pragma unroll
                for (int k = 0; k < 4; ++k) {
                    float4 p = pr4[lane + 64 * k];
                    s = fmaf(row[k].x, p.x, s);
                    s = fmaf(row[k].y, p.y, s);
                    s = fmaf(row[k].z, p.z, s);
                    s = fmaf(row[k].w, p.w, s);
                }
                part[u] = s;
            }
            #pragma unroll
            for (int off = 32; off > 0; off >>= 1) {
                part[0] += __shfl_down(part[0], off, 64);
                part[1] += __shfl_down(part[1], off, 64);
            }
            if (lane == 0) {
                #pragma unroll
                for (int u = 0; u < 2; ++u) {
                    const int n = n0 + nn + u;
                    float yii = pii * powers[n * L_N + l];
                    sv[n] = yii / (part[u] - yii + 1.0f);
                }
            }
        }
        if (tid < N_B) tails[tid] = 0.f;
    }
    __syncthreads();

    // ---- init: Q1 -> P[0] (f16 pairs) ----
    {
        const float s0l = sv[0] * LOG2E;
        const int jb = 8 * tid;
        float q[9];
        #pragma unroll
        for (int ii = 0; ii < 9; ++ii) {
            const int j = jb - 1 + ii;
            float v = 0.f;
            if (j >= 0 && j < T_N) v = 1.f - exp2f((1.f - p2t[j]) * s0l);
            q[ii] = v;
        }
        uint4 w;
        w.x = pk(q[1], q[0]); w.y = pk(q[3], q[2]);
        w.z = pk(q[5], q[4]); w.w = pk(q[7], q[6]);
        *(uint4*)&P[0][PADU + 4 * tid] = w;
        if (tid == 124) tails[0] = q[8];          // Q1[999]
    }
    __syncthreads();

    const int NB   = wr ? 126 : 64;               // 4-tap blocks (p-range)
    const int j0   = 512 * wr + 8 * lane;         // first output of this lane
    const int s4   = j0 >> 3;                     // window quad index
    const int jmxW = 512 * wr + 511;              // last output of this wave

    int A  = 0;                                   // support lower bound of Q_prev
    int cb = 0;
    for (int n = 1; n < N_B; ++n) {
        // ---- support bookkeeping (uniform across block) ----
        const float s = sv[n];
        const int kstar = (int)(100.f * log2f(KCUT / s)) + 1;   // conservative
        int dmin = 999 - kstar; if (dmin < 0) dmin = 0;
        const int Aprev = A;
        A += dmin;
        if (A > 999) break;                        // link dead: remaining tails = 0
        const int k0 = dmin >> 3;
        int kend = ((jmxW - Aprev) >> 3) + 1;      // per-wave upper tap bound
        if (kend > NB) kend = NB;
        int kcap = ((1023 - Aprev) >> 3) + 2;      // heavy kend + 1 (prefetch reach)
        if (kcap > 124) kcap = 124;

        // ---- phase R: taps (only quads [k0, kcap]) + bridge fix ----
        if (n >= 2 && wr == 1 && lane == 0)
            ((unsigned short*)&P[cb][PADU + 256])[1] = (unsigned short)bridge;
        if (tid >= k0 && tid <= kcap) {
            const float sl   = s * LOG2E;
            const float smul = s * LN2 * DT_F;
            const int t8 = 8 * tid;                // < 1000 since tid <= 124
            float4 pa = *(const float4*)&p2t[996 - t8];
            float4 pb = *(const float4*)&p2t[992 - t8];
            float r0 = smul * pa.w * exp2f((1.f - pa.w) * sl);
            float r1 = smul * pa.z * exp2f((1.f - pa.z) * sl);
            float r2 = smul * pa.y * exp2f((1.f - pa.y) * sl);
            float r3 = smul * pa.x * exp2f((1.f - pa.x) * sl);
            float r4 = smul * pb.w * exp2f((1.f - pb.w) * sl);
            float r5 = smul * pb.z * exp2f((1.f - pb.z) * sl);
            float r6 = smul * pb.y * exp2f((1.f - pb.y) * sl);
            float r7 = smul * pb.x * exp2f((1.f - pb.x) * sl);
            uint4 tw;
            tw.x = pk(r0, r1); tw.y = pk(r2, r3);
            tw.z = pk(r4, r5); tw.w = pk(r6, r7);
            *(uint4*)&T[4 * tid] = tw;
        }
        __syncthreads();

        // ---- phase C: conv over tap blocks k0..kend-1 ----
        const u32*   Pc = &P[cb][PADU];
        const uint4* P4 = (const uint4*)Pc;
        const uint4* T4 = (const uint4*)T;

        float a0 = 0.f, a1 = 0.f, a2 = 0.f, a3 = 0.f;
        float a4 = 0.f, a5 = 0.f, a6 = 0.f, a7 = 0.f;

        if (k0 < kend) {
            uint4 wc = P4[s4 - k0], wn = P4[s4 - k0 - 1];
            uint4 tc = T4[k0],      tn = T4[k0 + 1];

            #pragma unroll 2
            for (int k = k0; k < kend; ++k) {
                uint4 wnn = P4[s4 - k - 2];       // prefetch (pad-safe)
                uint4 tnn = T4[k + 2];            // broadcast (<=127 in bounds)
                u32 al;
                al = (tc.x >> 16) | (tc.y << 16);
                D8(wc.x, wc.y, wc.z, wc.w, tc.x, al);
                al = (tc.y >> 16) | (tc.z << 16);
                D8(wn.w, wc.x, wc.y, wc.z, tc.y, al);
                al = (tc.z >> 16) | (tc.w << 16);
                D8(wn.z, wn.w, wc.x, wc.y, tc.z, al);
                al = (tc.w >> 16) | (tn.x << 16);
                D8(wn.y, wn.z, wn.w, wc.x, tc.w, al);
                wc = wn; wn = wnn; tc = tn; tn = tnn;
            }
        }

        // ---- epilogue: pack to f16 pairs, write P_next ----
        {
            float qm1 = __shfl_up(a7, 1, 64);     // Q[j0-1] from neighbor
            if (lane == 0) qm1 = 0.f;             // light: Q[-1]=0; heavy: via bridge
            float b0 = (j0 + 0 < T_N) ? a0 : 0.f;
            float b1 = (j0 + 1 < T_N) ? a1 : 0.f;
            float b2 = (j0 + 2 < T_N) ? a2 : 0.f;
            float b3 = (j0 + 3 < T_N) ? a3 : 0.f;
            float b4 = (j0 + 4 < T_N) ? a4 : 0.f;
            float b5 = (j0 + 5 < T_N) ? a5 : 0.f;
            float b6 = (j0 + 6 < T_N) ? a6 : 0.f;
            float bm = (j0     <= T_N) ? qm1 : 0.f;
            uint4 w;
            w.x = pk(b0, bm); w.y = pk(b2, b1);
            w.z = pk(b4, b3); w.w = pk(b6, b5);
            *(uint4*)&P[cb ^ 1][PADU + 4 * s4] = w;
            if (wr == 1 && lane == 60) tails[n] = a7;   // out[999]
            if (wr == 0 && lane == 63)
                bridge = (u32)__builtin_bit_cast(unsigned short, (_Float16)a7); // Q[511]
        }
        __syncthreads();
        cb ^= 1;
    }
    __syncthreads();

    // ---- per-link loss contribution -> global atomic accumulate ----
    if (tid < N_B) {
        float tl   = tails[tid];
        float term = (tid < N_B - 1) ? tl * (powers[(tid + 1) * L_N + l] + 1.0f) : tl;
        if (tid == 0) term += powers[l] + 1.0f;
        #pragma unroll
        for (int off = 32; off > 0; off >>= 1) term += __shfl_down(term, off, 64);
        if (tid == 0) atomicAdd(out, term);
    }
}

extern "C" void kernel_launch(void* const* d_in, const int* in_sizes, int n_in,
                              void* d_out, int out_size, void* d_ws, size_t ws_size,
                              hipStream_t stream) {
    const float* powers   = (const float*)d_in[0];
    const float* pathloss = (const float*)d_in[1];
    float* out = (float*)d_out;

    hipMemsetAsync(out, 0, sizeof(float), stream);   // zero the accumulator (graph-capturable)
    scan_kernel<<<dim3(L_N), dim3(128), 0, stream>>>(powers, pathloss, out);
}

// Round 19
// 38.575 us; speedup vs baseline: 1.7522x; 1.0619x over previous
//
#include <hip/hip_runtime.h>
#include <math.h>

#define T_N   1000
#define L_N   1024
#define N_B   64
#define PADU  288          // zero-pad u32s (f16-pairs) below live P region
#define LOG2E 1.4426950408889634f
#define LN2   0.6931471805599453f
#define DT_F  0.01f
#define KCUT  5.0f         // tap cutoff: q negligible where 2^t*s > KCUT (e^-5)

typedef unsigned int u32;
typedef _Float16 h2_t __attribute__((ext_vector_type(2)));

__device__ __forceinline__ float dot2f(u32 t, u32 w, float c) {
#if __has_builtin(__builtin_amdgcn_fdot2)
    return __builtin_amdgcn_fdot2(__builtin_bit_cast(h2_t, t),
                                  __builtin_bit_cast(h2_t, w), c, false);
#else
    h2_t a = __builtin_bit_cast(h2_t, t), b = __builtin_bit_cast(h2_t, w);
    return fmaf((float)a.x, (float)b.x, fmaf((float)a.y, (float)b.y, c));
#endif
}

__device__ __forceinline__ u32 pk(float lo, float hi) {
    h2_t v; v.x = (_Float16)lo; v.y = (_Float16)hi;
    return __builtin_bit_cast(u32, v);
}

// ---------------- Kernel A: sinr[n,i] = y_ii / (y_ij + 1) ----------------
// 512 blocks x 2 links; row chunk in registers; n unrolled x4 for ILP.
__global__ __launch_bounds__(256) void sinr_kernel(const float* __restrict__ powers,
                                                   const float* __restrict__ pathloss,
                                                   float* __restrict__ sinr,
                                                   float* __restrict__ out) {
    const int tid  = threadIdx.x;
    const int wv   = tid >> 6;
    const int lane = tid & 63;
    const int i    = 2 * blockIdx.x + (wv & 1);
    const int n0   = 32 * (wv >> 1);

    if (blockIdx.x == 0 && tid == 0) out[0] = 0.f;   // scan runs after: safe

    const float4* row4g = (const float4*)(pathloss + i * L_N);
    float4 row[4];
    #pragma unroll
    for (int k = 0; k < 4; ++k) row[k] = row4g[lane + 64 * k];
    const float pii = pathloss[i * L_N + i];

    for (int nn = 0; nn < 32; nn += 4) {
        float part[4];
        #pragma unroll
        for (int u = 0; u < 4; ++u) {
            const float4* pr4 = (const float4*)(powers + (n0 + nn + u) * L_N);
            float s = 0.f;
            #pragma unroll
            for (int k = 0; k < 4; ++k) {
                float4 p = pr4[lane + 64 * k];
                s = fmaf(row[k].x, p.x, s);
                s = fmaf(row[k].y, p.y, s);
                s = fmaf(row[k].z, p.z, s);
                s = fmaf(row[k].w, p.w, s);
            }
            part[u] = s;
        }
        #pragma unroll
        for (int off = 32; off > 0; off >>= 1) {
            part[0] += __shfl_down(part[0], off, 64);
            part[1] += __shfl_down(part[1], off, 64);
            part[2] += __shfl_down(part[2], off, 64);
            part[3] += __shfl_down(part[3], off, 64);
        }
        if (lane == 0) {
            #pragma unroll
            for (int u = 0; u < 4; ++u) {
                const int n = n0 + nn + u;
                float yii = pii * powers[n * L_N + i];
                sinr[n * L_N + i] = yii / (part[u] - yii + 1.0f);
            }
        }
    }
}

// 8 dot2: outputs j0..j0+7 against one tap pair (TE) and its shifted twin (TO)
#define D8(W0, W1, W2, W3, TE, TO) do {                                      \
    a0 = dot2f(TE, W0, a0); a1 = dot2f(TO, W0, a1);                          \
    a2 = dot2f(TE, W1, a2); a3 = dot2f(TO, W1, a3);                          \
    a4 = dot2f(TE, W2, a4); a5 = dot2f(TO, W2, a5);                          \
    a6 = dot2f(TE, W3, a6); a7 = dot2f(TO, W3, a7);                          \
} while (0)

// ---------------- Kernel B: 2 waves/link, f16 dot2, support-tracked scan ----------------
// P[m] = f16x2 (lo=Q[2m], hi=Q[2m-1]); T[p] = f16x2 (lo=r[2p], hi=r[2p+1]).
// Support: r_n[d]==0 for d < dmin_n = 999 - k*(s_n), k* = 100*log2(KCUT/s);
// Q_n support = [A_n, 999], A_n = A_{n-1}+dmin_n; dead link (A>999) -> break.
// Two-sided trip: output j needs taps d <= j - A_prev -> per-wave kend.
// r-gen trimmed to quads [k0, kcap]; quads >=125 are permanent zeros.
__global__ __launch_bounds__(128) void scan_kernel(const float* __restrict__ powers,
                                                   const float* __restrict__ sinr,
                                                   float* __restrict__ out) {
    __shared__ __align__(16) float p2t[1024];
    __shared__ __align__(16) u32 P[2][PADU + 512];
    __shared__ __align__(16) u32 T[512];
    __shared__ float sv[N_B];
    __shared__ float tails[N_B];
    __shared__ u32 bridge;   // f16 bits of Q[511] (light wave lane 63's out)

    const int l    = blockIdx.x;
    const int tid  = threadIdx.x;                 // 0..127
    const int lane = tid & 63;
    const int wr   = ((tid >> 6) ^ (blockIdx.x & 1) ^ ((blockIdx.x >> 3) & 1)) & 1;

    // 2^t table (f32): 128 threads x 2 quads
    #pragma unroll
    for (int m = 0; m < 2; ++m) {
        const int jq = tid + 128 * m;
        float4 v;
        v.x = exp2f(0.01f * (float)(4 * jq + 0));
        v.y = exp2f(0.01f * (float)(4 * jq + 1));
        v.z = exp2f(0.01f * (float)(4 * jq + 2));
        v.w = exp2f(0.01f * (float)(4 * jq + 3));
        *(float4*)&p2t[4 * jq] = v;
    }
    if (tid < N_B) { sv[tid] = sinr[tid * L_N + l]; tails[tid] = 0.f; }
    for (int i = tid; i < PADU; i += 128) { P[0][i] = 0; P[1][i] = 0; }
    if (tid >= 125) *(uint4*)&T[4 * tid] = make_uint4(0u, 0u, 0u, 0u);  // d>=1000: permanent zeros
    __syncthreads();

    // ---- init: Q1 -> P[0] (f16 pairs) ----
    {
        const float s0l = sv[0] * LOG2E;
        const int jb = 8 * tid;
        float q[9];
        #pragma unroll
        for (int ii = 0; ii < 9; ++ii) {
            const int j = jb - 1 + ii;
            float v = 0.f;
            if (j >= 0 && j < T_N) v = 1.f - exp2f((1.f - p2t[j]) * s0l);
            q[ii] = v;
        }
        uint4 w;
        w.x = pk(q[1], q[0]); w.y = pk(q[3], q[2]);
        w.z = pk(q[5], q[4]); w.w = pk(q[7], q[6]);
        *(uint4*)&P[0][PADU + 4 * tid] = w;
        if (tid == 124) tails[0] = q[8];          // Q1[999]
    }
    __syncthreads();

    const int NB   = wr ? 126 : 64;               // 4-tap blocks (p-range)
    const int j0   = 512 * wr + 8 * lane;         // first output of this lane
    const int s4   = j0 >> 3;                     // window quad index
    const int jmxW = 512 * wr + 511;              // last output of this wave

    int A  = 0;                                   // support lower bound of Q_prev
    int cb = 0;
    for (int n = 1; n < N_B; ++n) {
        // ---- support bookkeeping (uniform across block) ----
        const float s = sv[n];
        const int kstar = (int)(100.f * log2f(KCUT / s)) + 1;   // conservative
        int dmin = 999 - kstar; if (dmin < 0) dmin = 0;
        const int Aprev = A;
        A += dmin;
        if (A > 999) break;                        // link dead: remaining tails = 0
        const int k0 = dmin >> 3;
        int kend = ((jmxW - Aprev) >> 3) + 1;      // per-wave upper tap bound
        if (kend > NB) kend = NB;
        int kcap = ((1023 - Aprev) >> 3) + 2;      // heavy kend + 1 (prefetch reach)
        if (kcap > 124) kcap = 124;

        // ---- phase R: taps (only quads [k0, kcap]) + bridge fix ----
        if (n >= 2 && wr == 1 && lane == 0)
            ((unsigned short*)&P[cb][PADU + 256])[1] = (unsigned short)bridge;
        if (tid >= k0 && tid <= kcap) {
            const float sl   = s * LOG2E;
            const float smul = s * LN2 * DT_F;
            const int t8 = 8 * tid;                // < 1000 since tid <= 124
            float4 pa = *(const float4*)&p2t[996 - t8];
            float4 pb = *(const float4*)&p2t[992 - t8];
            float r0 = smul * pa.w * exp2f((1.f - pa.w) * sl);
            float r1 = smul * pa.z * exp2f((1.f - pa.z) * sl);
            float r2 = smul * pa.y * exp2f((1.f - pa.y) * sl);
            float r3 = smul * pa.x * exp2f((1.f - pa.x) * sl);
            float r4 = smul * pb.w * exp2f((1.f - pb.w) * sl);
            float r5 = smul * pb.z * exp2f((1.f - pb.z) * sl);
            float r6 = smul * pb.y * exp2f((1.f - pb.y) * sl);
            float r7 = smul * pb.x * exp2f((1.f - pb.x) * sl);
            uint4 tw;
            tw.x = pk(r0, r1); tw.y = pk(r2, r3);
            tw.z = pk(r4, r5); tw.w = pk(r6, r7);
            *(uint4*)&T[4 * tid] = tw;
        }
        __syncthreads();

        // ---- phase C: conv over tap blocks k0..kend-1 ----
        const u32*   Pc = &P[cb][PADU];
        const uint4* P4 = (const uint4*)Pc;
        const uint4* T4 = (const uint4*)T;

        float a0 = 0.f, a1 = 0.f, a2 = 0.f, a3 = 0.f;
        float a4 = 0.f, a5 = 0.f, a6 = 0.f, a7 = 0.f;

        if (k0 < kend) {
            uint4 wc = P4[s4 - k0], wn = P4[s4 - k0 - 1];
            uint4 tc = T4[k0],      tn = T4[k0 + 1];

            #pragma unroll 2
            for (int k = k0; k < kend; ++k) {
                uint4 wnn = P4[s4 - k - 2];       // prefetch (pad-safe)
                uint4 tnn = T4[k + 2];            // broadcast (<=127 in bounds)
                u32 al;
                al = (tc.x >> 16) | (tc.y << 16);
                D8(wc.x, wc.y, wc.z, wc.w, tc.x, al);
                al = (tc.y >> 16) | (tc.z << 16);
                D8(wn.w, wc.x, wc.y, wc.z, tc.y, al);
                al = (tc.z >> 16) | (tc.w << 16);
                D8(wn.z, wn.w, wc.x, wc.y, tc.z, al);
                al = (tc.w >> 16) | (tn.x << 16);
                D8(wn.y, wn.z, wn.w, wc.x, tc.w, al);
                wc = wn; wn = wnn; tc = tn; tn = tnn;
            }
        }

        // ---- epilogue: pack to f16 pairs, write P_next ----
        {
            float qm1 = __shfl_up(a7, 1, 64);     // Q[j0-1] from neighbor
            if (lane == 0) qm1 = 0.f;             // light: Q[-1]=0; heavy: via bridge
            float b0 = (j0 + 0 < T_N) ? a0 : 0.f;
            float b1 = (j0 + 1 < T_N) ? a1 : 0.f;
            float b2 = (j0 + 2 < T_N) ? a2 : 0.f;
            float b3 = (j0 + 3 < T_N) ? a3 : 0.f;
            float b4 = (j0 + 4 < T_N) ? a4 : 0.f;
            float b5 = (j0 + 5 < T_N) ? a5 : 0.f;
            float b6 = (j0 + 6 < T_N) ? a6 : 0.f;
            float bm = (j0     <= T_N) ? qm1 : 0.f;
            uint4 w;
            w.x = pk(b0, bm); w.y = pk(b2, b1);
            w.z = pk(b4, b3); w.w = pk(b6, b5);
            *(uint4*)&P[cb ^ 1][PADU + 4 * s4] = w;
            if (wr == 1 && lane == 60) tails[n] = a7;   // out[999]
            if (wr == 0 && lane == 63)
                bridge = (u32)__builtin_bit_cast(unsigned short, (_Float16)a7); // Q[511]
        }
        __syncthreads();
        cb ^= 1;
    }
    __syncthreads();

    // ---- per-link loss contribution -> global atomic accumulate ----
    if (tid < N_B) {
        float tl   = tails[tid];
        float term = (tid < N_B - 1) ? tl * (powers[(tid + 1) * L_N + l] + 1.0f) : tl;
        if (tid == 0) term += powers[l] + 1.0f;
        #pragma unroll
        for (int off = 32; off > 0; off >>= 1) term += __shfl_down(term, off, 64);
        if (tid == 0) atomicAdd(out, term);
    }
}

extern "C" void kernel_launch(void* const* d_in, const int* in_sizes, int n_in,
                              void* d_out, int out_size, void* d_ws, size_t ws_size,
                              hipStream_t stream) {
    const float* powers   = (const float*)d_in[0];
    const float* pathloss = (const float*)d_in[1];
    float* sinr = (float*)d_ws;               // 64*1024 floats
    float* out  = (float*)d_out;

    sinr_kernel<<<dim3(L_N / 2), dim3(256), 0, stream>>>(powers, pathloss, sinr, out);
    scan_kernel<<<dim3(L_N), dim3(128), 0, stream>>>(powers, sinr, out);
}

// Round 20
// 38.191 us; speedup vs baseline: 1.7698x; 1.0100x over previous
//
#include <hip/hip_runtime.h>
#include <math.h>

#define T_N   1000
#define L_N   1024
#define N_B   64
#define PADU  288          // zero-pad u32s (f16-pairs) below live P region
#define LOG2E 1.4426950408889634f
#define LN2   0.6931471805599453f
#define DT_F  0.01f
#define KCUT  4.0f         // tap cutoff: q negligible where 2^t*s > KCUT (e^-4)

typedef unsigned int u32;
typedef _Float16 h2_t __attribute__((ext_vector_type(2)));

__device__ __forceinline__ float dot2f(u32 t, u32 w, float c) {
#if __has_builtin(__builtin_amdgcn_fdot2)
    return __builtin_amdgcn_fdot2(__builtin_bit_cast(h2_t, t),
                                  __builtin_bit_cast(h2_t, w), c, false);
#else
    h2_t a = __builtin_bit_cast(h2_t, t), b = __builtin_bit_cast(h2_t, w);
    return fmaf((float)a.x, (float)b.x, fmaf((float)a.y, (float)b.y, c));
#endif
}

__device__ __forceinline__ u32 pk(float lo, float hi) {
    h2_t v; v.x = (_Float16)lo; v.y = (_Float16)hi;
    return __builtin_bit_cast(u32, v);
}

// ---------------- Kernel A: sinr[n,i] = y_ii / (y_ij + 1) ----------------
// 512 blocks x 2 links; row chunk in registers; n unrolled x4 for ILP.
__global__ __launch_bounds__(256) void sinr_kernel(const float* __restrict__ powers,
                                                   const float* __restrict__ pathloss,
                                                   float* __restrict__ sinr,
                                                   float* __restrict__ out) {
    const int tid  = threadIdx.x;
    const int wv   = tid >> 6;
    const int lane = tid & 63;
    const int i    = 2 * blockIdx.x + (wv & 1);
    const int n0   = 32 * (wv >> 1);

    if (blockIdx.x == 0 && tid == 0) out[0] = 0.f;   // scan runs after: safe

    const float4* row4g = (const float4*)(pathloss + i * L_N);
    float4 row[4];
    #pragma unroll
    for (int k = 0; k < 4; ++k) row[k] = row4g[lane + 64 * k];
    const float pii = pathloss[i * L_N + i];

    for (int nn = 0; nn < 32; nn += 4) {
        float part[4];
        #pragma unroll
        for (int u = 0; u < 4; ++u) {
            const float4* pr4 = (const float4*)(powers + (n0 + nn + u) * L_N);
            float s = 0.f;
            #pragma unroll
            for (int k = 0; k < 4; ++k) {
                float4 p = pr4[lane + 64 * k];
                s = fmaf(row[k].x, p.x, s);
                s = fmaf(row[k].y, p.y, s);
                s = fmaf(row[k].z, p.z, s);
                s = fmaf(row[k].w, p.w, s);
            }
            part[u] = s;
        }
        #pragma unroll
        for (int off = 32; off > 0; off >>= 1) {
            part[0] += __shfl_down(part[0], off, 64);
            part[1] += __shfl_down(part[1], off, 64);
            part[2] += __shfl_down(part[2], off, 64);
            part[3] += __shfl_down(part[3], off, 64);
        }
        if (lane == 0) {
            #pragma unroll
            for (int u = 0; u < 4; ++u) {
                const int n = n0 + nn + u;
                float yii = pii * powers[n * L_N + i];
                sinr[n * L_N + i] = yii / (part[u] - yii + 1.0f);
            }
        }
    }
}

// 8 dot2: outputs j0..j0+7 against one tap pair (TE) and its shifted twin (TO)
#define D8(W0, W1, W2, W3, TE, TO) do {                                      \
    a0 = dot2f(TE, W0, a0); a1 = dot2f(TO, W0, a1);                          \
    a2 = dot2f(TE, W1, a2); a3 = dot2f(TO, W1, a3);                          \
    a4 = dot2f(TE, W2, a4); a5 = dot2f(TO, W2, a5);                          \
    a6 = dot2f(TE, W3, a6); a7 = dot2f(TO, W3, a7);                          \
} while (0)

// ---------------- Kernel B: 2 waves/link, f16 dot2, support-tracked scan ----------------
// P[m] = f16x2 (lo=Q[2m], hi=Q[2m-1]); T[p] = f16x2 (lo=r[2p], hi=r[2p+1]).
// Support: r_n[d]==0 for d < dmin_n = 999 - k*(s_n), k* = 100*log2(KCUT/s);
// Q_n support = [A_n, 999], A_n = A_{n-1}+dmin_n; dead link (A>999) -> break.
// Two-sided trip: output j needs taps d <= j - A_prev -> per-wave kend.
// r-gen trimmed to quads [k0, kcap]; quads >=125 are permanent zeros.
__global__ __launch_bounds__(128) void scan_kernel(const float* __restrict__ powers,
                                                   const float* __restrict__ sinr,
                                                   float* __restrict__ out) {
    __shared__ __align__(16) float p2t[1024];
    __shared__ __align__(16) u32 P[2][PADU + 512];
    __shared__ __align__(16) u32 T[512];
    __shared__ float sv[N_B];
    __shared__ float tails[N_B];
    __shared__ u32 bridge;   // f16 bits of Q[511] (light wave lane 63's out)

    const int l    = blockIdx.x;
    const int tid  = threadIdx.x;                 // 0..127
    const int lane = tid & 63;
    const int wr   = ((tid >> 6) ^ (blockIdx.x & 1) ^ ((blockIdx.x >> 3) & 1)) & 1;

    // 2^t table (f32): 128 threads x 2 quads
    #pragma unroll
    for (int m = 0; m < 2; ++m) {
        const int jq = tid + 128 * m;
        float4 v;
        v.x = exp2f(0.01f * (float)(4 * jq + 0));
        v.y = exp2f(0.01f * (float)(4 * jq + 1));
        v.z = exp2f(0.01f * (float)(4 * jq + 2));
        v.w = exp2f(0.01f * (float)(4 * jq + 3));
        *(float4*)&p2t[4 * jq] = v;
    }
    if (tid < N_B) { sv[tid] = sinr[tid * L_N + l]; tails[tid] = 0.f; }
    for (int i = tid; i < PADU; i += 128) { P[0][i] = 0; P[1][i] = 0; }
    if (tid >= 125) *(uint4*)&T[4 * tid] = make_uint4(0u, 0u, 0u, 0u);  // d>=1000: permanent zeros
    __syncthreads();

    // ---- init: Q1 -> P[0] (f16 pairs) ----
    {
        const float s0l = sv[0] * LOG2E;
        const int jb = 8 * tid;
        float q[9];
        #pragma unroll
        for (int ii = 0; ii < 9; ++ii) {
            const int j = jb - 1 + ii;
            float v = 0.f;
            if (j >= 0 && j < T_N) v = 1.f - exp2f((1.f - p2t[j]) * s0l);
            q[ii] = v;
        }
        uint4 w;
        w.x = pk(q[1], q[0]); w.y = pk(q[3], q[2]);
        w.z = pk(q[5], q[4]); w.w = pk(q[7], q[6]);
        *(uint4*)&P[0][PADU + 4 * tid] = w;
        if (tid == 124) tails[0] = q[8];          // Q1[999]
    }
    __syncthreads();

    const int NB   = wr ? 126 : 64;               // 4-tap blocks (p-range)
    const int j0   = 512 * wr + 8 * lane;         // first output of this lane
    const int s4   = j0 >> 3;                     // window quad index
    const int jmxW = 512 * wr + 511;              // last output of this wave

    int A  = 0;                                   // support lower bound of Q_prev
    int cb = 0;
    for (int n = 1; n < N_B; ++n) {
        // ---- support bookkeeping (uniform across block) ----
        const float s = sv[n];
        const int kstar = (int)(100.f * log2f(KCUT / s)) + 1;   // conservative
        int dmin = 999 - kstar; if (dmin < 0) dmin = 0;
        const int Aprev = A;
        A += dmin;
        if (A > 999) break;                        // link dead: remaining tails = 0
        const int k0 = dmin >> 3;
        int kend = ((jmxW - Aprev) >> 3) + 1;      // per-wave upper tap bound
        if (kend > NB) kend = NB;
        int kcap = ((1023 - Aprev) >> 3) + 2;      // heavy kend + 1 (prefetch reach)
        if (kcap > 124) kcap = 124;

        // ---- phase R: taps (only quads [k0, kcap]) + bridge fix ----
        if (n >= 2 && wr == 1 && lane == 0)
            ((unsigned short*)&P[cb][PADU + 256])[1] = (unsigned short)bridge;
        if (tid >= k0 && tid <= kcap) {
            const float sl   = s * LOG2E;
            const float smul = s * LN2 * DT_F;
            const int t8 = 8 * tid;                // < 1000 since tid <= 124
            float4 pa = *(const float4*)&p2t[996 - t8];
            float4 pb = *(const float4*)&p2t[992 - t8];
            float r0 = smul * pa.w * exp2f((1.f - pa.w) * sl);
            float r1 = smul * pa.z * exp2f((1.f - pa.z) * sl);
            float r2 = smul * pa.y * exp2f((1.f - pa.y) * sl);
            float r3 = smul * pa.x * exp2f((1.f - pa.x) * sl);
            float r4 = smul * pb.w * exp2f((1.f - pb.w) * sl);
            float r5 = smul * pb.z * exp2f((1.f - pb.z) * sl);
            float r6 = smul * pb.y * exp2f((1.f - pb.y) * sl);
            float r7 = smul * pb.x * exp2f((1.f - pb.x) * sl);
            uint4 tw;
            tw.x = pk(r0, r1); tw.y = pk(r2, r3);
            tw.z = pk(r4, r5); tw.w = pk(r6, r7);
            *(uint4*)&T[4 * tid] = tw;
        }
        __syncthreads();

        // ---- phase C: conv over tap blocks k0..kend-1 ----
        const u32*   Pc = &P[cb][PADU];
        const uint4* P4 = (const uint4*)Pc;
        const uint4* T4 = (const uint4*)T;

        float a0 = 0.f, a1 = 0.f, a2 = 0.f, a3 = 0.f;
        float a4 = 0.f, a5 = 0.f, a6 = 0.f, a7 = 0.f;

        if (k0 < kend) {
            uint4 wc = P4[s4 - k0], wn = P4[s4 - k0 - 1];
            uint4 tc = T4[k0],      tn = T4[k0 + 1];

            #pragma unroll 2
            for (int k = k0; k < kend; ++k) {
                uint4 wnn = P4[s4 - k - 2];       // prefetch (pad-safe)
                uint4 tnn = T4[k + 2];            // broadcast (<=127 in bounds)
                u32 al;
                al = (tc.x >> 16) | (tc.y << 16);
                D8(wc.x, wc.y, wc.z, wc.w, tc.x, al);
                al = (tc.y >> 16) | (tc.z << 16);
                D8(wn.w, wc.x, wc.y, wc.z, tc.y, al);
                al = (tc.z >> 16) | (tc.w << 16);
                D8(wn.z, wn.w, wc.x, wc.y, tc.z, al);
                al = (tc.w >> 16) | (tn.x << 16);
                D8(wn.y, wn.z, wn.w, wc.x, tc.w, al);
                wc = wn; wn = wnn; tc = tn; tn = tnn;
            }
        }

        // ---- epilogue: pack to f16 pairs, write P_next ----
        {
            float qm1 = __shfl_up(a7, 1, 64);     // Q[j0-1] from neighbor
            if (lane == 0) qm1 = 0.f;             // light: Q[-1]=0; heavy: via bridge
            float b0 = (j0 + 0 < T_N) ? a0 : 0.f;
            float b1 = (j0 + 1 < T_N) ? a1 : 0.f;
            float b2 = (j0 + 2 < T_N) ? a2 : 0.f;
            float b3 = (j0 + 3 < T_N) ? a3 : 0.f;
            float b4 = (j0 + 4 < T_N) ? a4 : 0.f;
            float b5 = (j0 + 5 < T_N) ? a5 : 0.f;
            float b6 = (j0 + 6 < T_N) ? a6 : 0.f;
            float bm = (j0     <= T_N) ? qm1 : 0.f;
            uint4 w;
            w.x = pk(b0, bm); w.y = pk(b2, b1);
            w.z = pk(b4, b3); w.w = pk(b6, b5);
            *(uint4*)&P[cb ^ 1][PADU + 4 * s4] = w;
            if (wr == 1 && lane == 60) tails[n] = a7;   // out[999]
            if (wr == 0 && lane == 63)
                bridge = (u32)__builtin_bit_cast(unsigned short, (_Float16)a7); // Q[511]
        }
        __syncthreads();
        cb ^= 1;
    }
    __syncthreads();

    // ---- per-link loss contribution -> global atomic accumulate ----
    if (tid < N_B) {
        float tl   = tails[tid];
        float term = (tid < N_B - 1) ? tl * (powers[(tid + 1) * L_N + l] + 1.0f) : tl;
        if (tid == 0) term += powers[l] + 1.0f;
        #pragma unroll
        for (int off = 32; off > 0; off >>= 1) term += __shfl_down(term, off, 64);
        if (tid == 0) atomicAdd(out, term);
    }
}

extern "C" void kernel_launch(void* const* d_in, const int* in_sizes, int n_in,
                              void* d_out, int out_size, void* d_ws, size_t ws_size,
                              hipStream_t stream) {
    const float* powers   = (const float*)d_in[0];
    const float* pathloss = (const float*)d_in[1];
    float* sinr = (float*)d_ws;               // 64*1024 floats
    float* out  = (float*)d_out;

    sinr_kernel<<<dim3(L_N / 2), dim3(256), 0, stream>>>(powers, pathloss, sinr, out);
    scan_kernel<<<dim3(L_N), dim3(128), 0, stream>>>(powers, sinr, out);
}